// Round 9
// baseline (329.341 us; speedup 1.0000x reference)
//
#include <hip/hip_runtime.h>

// VQ-VAE codebook quantization, MI355X (gfx950)
// z: [32, 256, 32, 32] fp32 ; codebook: [1024, 256] fp32
// outputs (concat fp32): z_q [32,256,32,32] (8388608) | idx [32768] | loss [1]
//
// Correctness contract: idx must match numpy's fp32 argmin of
//   dist = fl( fl(znorm + enorm) - 2*dot ),  ties -> lowest index.
// The +znorm(~256) term quantizes dist to ulp ~3e-5; replicating that
// quantization (NOT dropping the constant term) is what makes ties match.
//
// R9 theory: R6/R7/R8 all plateau at 245-270us, VALUBusy 56-59%, despite
// different staging structures. Shared cause: the A-operand s_loads (SMEM)
// share lgkmcnt with ds_read, and SMEM completes OUT-OF-ORDER -> compiler
// must emit s_waitcnt lgkmcnt(0) before every dd-group's FMA block, fully
// draining the LDS pipe 8x per step. No ds_read pipelining survives that.
// Fix (one variable vs R8): A-loads become VMEM broadcasts (drop the
// readfirstlane; divergent-per-thread, uniform-per-wave address -> one
// cache line per load, L1/L2-hot). A waits on vmcnt, E waits on in-order
// fine-grained lgkmcnt -> both pipelines flow under the unrolled dd loop.

#define D_DIM   256
#define K_CODES 1024
#define HW      1024
#define MT      64      // positions per block
#define NT      512     // codes per N-chunk (2 chunks)
#define BK      8       // d-rows staged per step
#define THREADS 512
#define NSTEP   64      // 2 chunks * 32 steps

#define ZQ_OFF   0
#define IDX_OFF  8388608
#define LOSS_OFF 8421376

// Es[2][8][512] + znorm_s[64] + bestm[64]
#define SMEM_FLOATS (2*BK*NT + MT + MT)   // 8192+128 = 8320
#define SMEM_BYTES  (SMEM_FLOATS * 4)     // 33280 B -> 2+ blocks/CU fit

extern __shared__ float smem[];

// ws: enorm[k] = fp32 sum of cb[k][d]^2 (own order; ~ulp(8e-5) agreement is enough)
__global__ void enorm_kernel(const float* __restrict__ cb, float* __restrict__ enorm) {
    int gt = blockIdx.x * blockDim.x + threadIdx.x;
    int k = gt >> 6;
    int lane = gt & 63;
    const float4* row = (const float4*)(cb + (size_t)k * D_DIM);
    float4 v = row[lane];
    float s = fmaf(v.x, v.x, fmaf(v.y, v.y, fmaf(v.z, v.z, v.w * v.w)));
    #pragma unroll
    for (int off = 32; off; off >>= 1) s += __shfl_xor(s, off);
    if (lane == 0) enorm[k] = s;
}

__global__ __launch_bounds__(THREADS, 2)   // proven: <=128-VGPR budget, no spill
void vq_kernel(
        const float* __restrict__ z, const float* __restrict__ cb,
        const float* __restrict__ enorm, float* __restrict__ out)
{
    float* Es      = smem;                            // [2][8][512] codebook dbuf
    float* znorm_s = smem + 2 * BK * NT;              // [64]
    int*   bestm   = (int*)(smem + 2 * BK * NT + MT); // [64]

    const int t   = threadIdx.x;
    const int blk = blockIdx.x;          // 512 blocks = 2/CU
    const int b   = blk >> 4;
    const int p0  = (blk & 15) * MT;
    const float* zb = z + (size_t)b * D_DIM * HW;

    // staging: thread t stages code (chunk*512 + t), 8 d-values per step.
    const float* cbp = cb + (size_t)t * D_DIM;

    // gload step 0 early (hides under znorm)
    float4 s0a = *(const float4*)(cbp);
    float4 s0b = *(const float4*)(cbp + 4);

    // ---- znorm[m] = fp64 sum over d of z[d][p0+m]^2 (global, coalesced) ----
    // (fp64 vs numpy's pairwise-fp32 differs by <=1-2 ulp of ~256; uniform
    //  exact-ulp shift per row -> argmin invariant.)
    {
        int m = t & (MT - 1), q = t >> 6;
        const float* col = zb + p0 + m;
        double zp = 0.0;
        #pragma unroll 8
        for (int d = q * 32; d < q * 32 + 32; ++d) {
            double v = (double)col[(size_t)d * HW];
            zp += v * v;
        }
        double* zscr = (double*)Es;                  // 512 doubles = 4 KB scratch
        zscr[q * MT + m] = zp;
    }
    __syncthreads();
    if (t < MT) {
        double* zscr = (double*)Es;
        double s = 0.0;
        #pragma unroll
        for (int q = 0; q < 8; ++q) s += zscr[q * MT + t];
        znorm_s[t] = (float)s;
    }
    __syncthreads();   // zscr reads done before buf0 staging overwrites them

    // ---- stage step 0 into buf0; issue gload step 1 ----
    {
        Es[0 * NT + t] = s0a.x;  Es[1 * NT + t] = s0a.y;
        Es[2 * NT + t] = s0a.z;  Es[3 * NT + t] = s0a.w;
        Es[4 * NT + t] = s0b.x;  Es[5 * NT + t] = s0b.y;
        Es[6 * NT + t] = s0b.z;  Es[7 * NT + t] = s0b.w;
    }
    float4 svA = *(const float4*)(cbp + BK);        // step 1 data
    float4 svB = *(const float4*)(cbp + BK + 4);
    __syncthreads();   // buf0 visible

    // ---- thread layout: wave w owns m rows w*8..+7 (wave-uniform A);
    //      lane tx owns codes {tx*4..+3} u {256+tx*4..+3} of each 512-chunk.
    const int tx = t & 63;
    const int m_base = (t >> 6) * 8;
    const int kx4 = tx * 4;

    float bestv[8]; int besti[8];
    #pragma unroll
    for (int i = 0; i < 8; ++i) { bestv[i] = 3.4e38f; besti[i] = 0; }

    float acc[8][8];
    #pragma unroll
    for (int i = 0; i < 8; ++i)
        #pragma unroll
        for (int j = 0; j < 8; ++j) acc[i][j] = 0.f;

    // wave-uniform (thread-divergent to the compiler -> VMEM broadcast path)
    const float* zrow = zb + p0 + m_base;

    int cur = 0;
    for (int g = 0; g < NSTEP; ++g) {
        // write step g+1 data into buf^1 (its last readers finished at g-1)
        if (g < NSTEP - 1) {
            float* En = Es + (cur ^ 1) * (BK * NT);
            En[0 * NT + t] = svA.x;  En[1 * NT + t] = svA.y;
            En[2 * NT + t] = svA.z;  En[3 * NT + t] = svA.w;
            En[4 * NT + t] = svB.x;  En[5 * NT + t] = svB.y;
            En[6 * NT + t] = svB.z;  En[7 * NT + t] = svB.w;
        }
        // issue gload for step g+2 (consumed as LDS-write at g+1)
        {
            const int gn = (g + 2 < NSTEP) ? g + 2 : NSTEP - 1;
            const float* p = cbp + (((size_t)(gn >> 5)) << 17) + ((gn & 31) << 3);
            svA = *(const float4*)(p);
            svB = *(const float4*)(p + 4);
        }

        const int dk = (g & 31) * BK;
        const float* Ec = Es + cur * (BK * NT);
        #pragma unroll
        for (int dd = 0; dd < BK; ++dd) {
            // A-operand: VMEM broadcast (all lanes same addr -> 1 line, L1/L2-hot).
            // vmcnt domain, independent of the e-reads' in-order lgkmcnt.
            const float* ar = zrow + (size_t)(dk + dd) * HW;
            float a[8], e[8];
            *(float4*)(a)     = *(const float4*)(ar);
            *(float4*)(a + 4) = *(const float4*)(ar + 4);
            const float* Er = Ec + dd * NT + kx4;
            *(float4*)(e)     = *(const float4*)(Er);         // codes kx4..+3
            *(float4*)(e + 4) = *(const float4*)(Er + 256);   // codes 256+kx4..+3
            #pragma unroll
            for (int i = 0; i < 8; ++i)
                #pragma unroll
                for (int j = 0; j < 8; ++j)
                    acc[i][j] = fmaf(a[i], e[j], acc[i][j]);
        }

        if ((g & 31) == 31) {
            // chunk epilogue: dist = fl( fl(znorm + enorm) - 2*dot ), np-style
            const int c = g >> 5;
            #pragma unroll
            for (int j = 0; j < 8; ++j) {
                const int kidx = c * NT + ((j < 4) ? (kx4 + j) : (252 + kx4 + j));
                const float bn = enorm[kidx];
                #pragma unroll
                for (int i = 0; i < 8; ++i) {
                    float A   = znorm_s[m_base + i] + bn;  // rounds at ~256 scale
                    float val = A - 2.0f * acc[i][j];      // 2*acc exact; 1 rounding
                    if (val < bestv[i] || (val == bestv[i] && kidx < besti[i])) {
                        bestv[i] = val; besti[i] = kidx;
                    }
                }
            }
            #pragma unroll
            for (int i = 0; i < 8; ++i)
                #pragma unroll
                for (int j = 0; j < 8; ++j) acc[i][j] = 0.f;
        }
        __syncthreads();
        cur ^= 1;
    }

    // ---- argmin reduce across the full wave (64 lanes), lowest index ties ----
    #pragma unroll
    for (int i = 0; i < 8; ++i) {
        float v = bestv[i]; int ix = besti[i];
        #pragma unroll
        for (int off = 32; off; off >>= 1) {
            float ov = __shfl_xor(v, off);
            int   oi = __shfl_xor(ix, off);
            if (ov < v || (ov == v && oi < ix)) { v = ov; ix = oi; }
        }
        if (tx == 0) {
            bestm[m_base + i] = ix;
            out[IDX_OFF + (size_t)blk * MT + m_base + i] = (float)ix;
        }
    }
    __syncthreads();

    // ---- epilogue: gather codebook rows (L2), z from global (L2-hot),
    //      write z_q coalesced, loss ----
    float lsum = 0.f;
    const size_t zq_base = (size_t)b * D_DIM * HW + p0;
    for (int i2 = t; i2 < D_DIM * MT / 4; i2 += THREADS) {
        int p = i2 & (MT - 1), d4 = i2 >> 6;
        int idx = bestm[p];
        float4 cv = *(const float4*)(cb + (size_t)idx * D_DIM + d4 * 4);
        const float* zp = zb + p0 + p;
        float z0 = zp[(size_t)(d4 * 4 + 0) * HW];
        float z1 = zp[(size_t)(d4 * 4 + 1) * HW];
        float z2 = zp[(size_t)(d4 * 4 + 2) * HW];
        float z3 = zp[(size_t)(d4 * 4 + 3) * HW];
        float e0 = cv.x - z0, e1 = cv.y - z1, e2 = cv.z - z2, e3 = cv.w - z3;
        lsum = fmaf(e0, e0, lsum); lsum = fmaf(e1, e1, lsum);
        lsum = fmaf(e2, e2, lsum); lsum = fmaf(e3, e3, lsum);
        out[zq_base + (size_t)(d4 * 4 + 0) * HW + p] = cv.x;
        out[zq_base + (size_t)(d4 * 4 + 1) * HW + p] = cv.y;
        out[zq_base + (size_t)(d4 * 4 + 2) * HW + p] = cv.z;
        out[zq_base + (size_t)(d4 * 4 + 3) * HW + p] = cv.w;
    }
    #pragma unroll
    for (int off = 32; off; off >>= 1) lsum += __shfl_xor(lsum, off);
    __syncthreads();
    if ((t & 63) == 0) Es[t >> 6] = lsum;
    __syncthreads();
    if (t == 0) {
        float s = 0.f;
        #pragma unroll
        for (int w = 0; w < 8; ++w) s += Es[w];
        atomicAdd(out + LOSS_OFF, s * (1.25f / 8388608.f));
    }
}

extern "C" void kernel_launch(void* const* d_in, const int* in_sizes, int n_in,
                              void* d_out, int out_size, void* d_ws, size_t ws_size,
                              hipStream_t stream) {
    const float* z  = (const float*)d_in[0];
    const float* cb = (const float*)d_in[1];
    float* out = (float*)d_out;
    float* enorm = (float*)d_ws;

    hipMemsetAsync(out + LOSS_OFF, 0, sizeof(float), stream);

    enorm_kernel<<<256, 256, 0, stream>>>(cb, enorm);

    hipFuncSetAttribute((const void*)vq_kernel,
                        hipFuncAttributeMaxDynamicSharedMemorySize, SMEM_BYTES);
    vq_kernel<<<512, THREADS, SMEM_BYTES, stream>>>(z, cb, enorm, out);
}

// Round 12
// 273.463 us; speedup vs baseline: 1.2043x; 1.2043x over previous
//
#include <hip/hip_runtime.h>
#include <stdint.h>

// VQ-VAE codebook quantization, MI355X (gfx950) — MFMA filter + exact rescore.
// z: [32, 256, 32, 32] fp32 ; codebook: [1024, 256] fp32
// outputs (concat fp32): z_q [32,256,32,32] (8388608) | idx [32768] | loss [1]
//
// R12 = R11 with the LDS swizzle fixed. R11's key ((code&7)<<4) was 3 bits
// XOR'd into the 2-bit slot field of a 64B row -> offsets escaped the row
// (collisions + uninitialized holes -> NaN acc -> empty candidate lists ->
// idx=-1, absmax exactly 1024). New key ((code>>1)&3)<<4 stays in-row and
// gives 2 lanes/bank on fragment reads (conflict-free).
//
// Design:
//  1) bf16 truncation-split z = hz + lz + s (|s| <= 2^-14 |z|); 3-pass MFMA
//     dot3 = hz*he + hz*le + lz*he. |dot - dot3| <= 3*2^-14*||z||*||e|| + 1e-6,
//     ||e|| <= sqrt(256)/1024 (uniform init bound).
//  2) per-row filter: keep codes with approx dist <= min + Delta_m,
//     Delta_m = 1.15e-5*sqrt(znorm) + 9.5e-5 (2x the 2*err capture bound).
//  3) exact fp32 FMA rescore of candidates from LDS z-tile; two-stage
//     u32 atomicMin merge (val bits, then lowest k) == numpy tie semantics.
//     List overflow -> brute-force exact fallback.

#define D_DIM   256
#define HW      1024
#define MT      64       // m rows per block
#define THREADS 512
#define LIST_CAP 2048

#define ZQ_OFF   0
#define IDX_OFF  8388608
#define LOSS_OFF 8421376

typedef __attribute__((ext_vector_type(8))) short  short8;
typedef __attribute__((ext_vector_type(4))) float  f32x4;
typedef __attribute__((ext_vector_type(4))) unsigned int u32x4;

// ---- LDS layout (bytes) ----
#define ZFP_ROW   264                    // 256 d + 8 pad floats (16B-aligned rows)
#define OFF_ZFP   0                      // 64*264*4 = 67584
#define OFF_HEB   67584                  // 256 codes * 64 B = 16384 (swizzled bf16)
#define OFF_LEB   83968                  // 16384
#define OFF_HZA   100352                 // 64 m * 64 B = 4096
#define OFF_LZA   104448                 // 4096
#define OFF_LIST  108544                 // 2048 * 4 = 8192
#define OFF_ZN    116736                 // 64 f32
#define OFF_DLT   116992                 // 64 f32
#define OFF_RMIN  117248                 // 64 u32
#define OFF_RBV   117504                 // 64 u32
#define OFF_RBK   117760                 // 64 u32
#define OFF_BESTM 118016                 // 64 i32
#define OFF_CNT   118272                 // i32
#define OFF_OVF   118276                 // i32
#define SMEM_BYTES 118288

// in-row XOR swizzle: slot(u) ^= (row>>1)&3  (bits 4-5 only, bijective in 64B)
#define SWZ(rowi, u16) (((u16) ^ ((((rowi) >> 1) & 3) << 4)))

extern __shared__ char smc[];

// ws: enorm[k] = fp32 sum of cb[k][d]^2
__global__ void enorm_kernel(const float* __restrict__ cb, float* __restrict__ enorm) {
    int gt = blockIdx.x * blockDim.x + threadIdx.x;
    int k = gt >> 6;
    int lane = gt & 63;
    const float4* row = (const float4*)(cb + (size_t)k * D_DIM);
    float4 v = row[lane];
    float s = fmaf(v.x, v.x, fmaf(v.y, v.y, fmaf(v.z, v.z, v.w * v.w)));
    #pragma unroll
    for (int off = 32; off; off >>= 1) s += __shfl_xor(s, off);
    if (lane == 0) enorm[k] = s;
}

__device__ __forceinline__ void split2(float a, float b, unsigned &hi, unsigned &lo) {
    unsigned ba = __float_as_uint(a), bb = __float_as_uint(b);
    unsigned ha = ba & 0xFFFF0000u, hb = bb & 0xFFFF0000u;
    float ra = a - __uint_as_float(ha);     // exact (same-exponent split)
    float rb = b - __uint_as_float(hb);
    hi = (ha >> 16) | hb;                   // bf16 pair: low half = first elem
    lo = (__float_as_uint(ra) >> 16) | (__float_as_uint(rb) & 0xFFFF0000u);
}

// pack 8 consecutive floats into bf16-hi/lo u32x4 fragments
__device__ __forceinline__ void split8(const float* src, u32x4 &hv, u32x4 &lv) {
    f32x4 A0 = *(const f32x4*)(src);
    f32x4 A1 = *(const f32x4*)(src + 4);
    unsigned h0, l0, h1, l1, h2, l2, h3, l3;
    split2(A0.x, A0.y, h0, l0);
    split2(A0.z, A0.w, h1, l1);
    split2(A1.x, A1.y, h2, l2);
    split2(A1.z, A1.w, h3, l3);
    hv.x = h0; hv.y = h1; hv.z = h2; hv.w = h3;
    lv.x = l0; lv.y = l1; lv.z = l2; lv.w = l3;
}

// exact np-style distance; __noinline__ so both rescore passes produce
// BIT-IDENTICAL values (needed for the equality-gated k-merge).
__device__ __noinline__ float exact_val(const char* sm, const float* cb,
                                        const float* enorm, int m, int k) {
    const float* zr = (const float*)(sm + OFF_ZFP) + (size_t)m * ZFP_ROW;
    const float* cr = cb + (size_t)k * D_DIM;
    float dot = 0.f;
    #pragma unroll 8
    for (int d = 0; d < D_DIM; ++d) dot = fmaf(zr[d], cr[d], dot);
    float A = ((const float*)(sm + OFF_ZN))[m] + enorm[k];
    return A - 2.0f * dot;
}

__global__ __launch_bounds__(THREADS, 2)
void vq_kernel(const float* __restrict__ z, const float* __restrict__ cb,
               const float* __restrict__ enorm, float* __restrict__ out)
{
    char* sm = smc;
    float*    zfp   = (float*)(sm + OFF_ZFP);
    float*    znS   = (float*)(sm + OFF_ZN);
    float*    dltS  = (float*)(sm + OFF_DLT);
    unsigned* rminU = (unsigned*)(sm + OFF_RMIN);
    unsigned* rbv   = (unsigned*)(sm + OFF_RBV);
    unsigned* rbk   = (unsigned*)(sm + OFF_RBK);
    int*      bestm = (int*)(sm + OFF_BESTM);
    unsigned* listU = (unsigned*)(sm + OFF_LIST);
    int*      cntP  = (int*)(sm + OFF_CNT);
    int*      ovfP  = (int*)(sm + OFF_OVF);

    const int t   = threadIdx.x;
    const int blk = blockIdx.x;              // 512 blocks
    const int b   = blk >> 4;
    const int p0  = (blk & 15) * MT;
    const float* zb = z + (size_t)b * D_DIM * HW;

    // ---- 1) stage z tile transposed: zfp[m][d] (z read coalesced) ----
    #pragma unroll
    for (int r = 0; r < 8; ++r) {
        int d = (t >> 4) + r * 32;
        int m4 = (t & 15) * 4;
        f32x4 v = *(const f32x4*)(zb + (size_t)d * HW + p0 + m4);
        zfp[(m4 + 0) * ZFP_ROW + d] = v.x;
        zfp[(m4 + 1) * ZFP_ROW + d] = v.y;
        zfp[(m4 + 2) * ZFP_ROW + d] = v.z;
        zfp[(m4 + 3) * ZFP_ROW + d] = v.w;
    }
    __syncthreads();

    // ---- 2) znorm (fp64; <=1-2 ulp vs numpy — uniform per-row shift) ----
    {
        int m = t & 63, q = t >> 6;
        const float* zr = zfp + m * ZFP_ROW + q * 32;
        double zp = 0.0;
        #pragma unroll 8
        for (int d = 0; d < 32; ++d) { double v = (double)zr[d]; zp += v * v; }
        double* zscr = (double*)(sm + OFF_HEB);        // scratch in B area
        zscr[q * 64 + m] = zp;
    }
    __syncthreads();
    if (t < 64) {
        double* zscr = (double*)(sm + OFF_HEB);
        double s = 0.0;
        #pragma unroll
        for (int q = 0; q < 8; ++q) s += zscr[q * 64 + t];
        float zn = (float)s;
        znS[t]  = zn;
        dltS[t] = 1.15e-5f * sqrtf(zn) + 9.5e-5f;      // rigorous capture window
        rbv[t]  = 0x7f800000u;                         // +inf bits
        rbk[t]  = 0xFFFFFFFFu;
    }
    if (t == 0) { *cntP = 0; *ovfP = 0; }
    __syncthreads();   // zscr reads done before B staging overwrites

    const int l   = t & 63;
    const int wid = t >> 6;
    const int wm  = wid & 3;      // 4 m-subtiles of 16
    const int wc  = wid >> 2;     // 2 code-halves of 128 (within 256-chunk)
    const int l15 = l & 15;

    // ---- 3) kc loop: 4 quarters of 256 codes ----
    for (int kc = 0; kc < 4; ++kc) {
        if (t < 64) rminU[t] = 0x7f800000u;

        f32x4 acc[8];
        #pragma unroll
        for (int sc = 0; sc < 8; ++sc) acc[sc] = (f32x4){0.f, 0.f, 0.f, 0.f};

        for (int s = 0; s < 8; ++s) {
            const int d0 = s * 32;
            __syncthreads();   // prior compute done; (kc-top: rmin reset visible)

            // stage B: 256 codes x 32 d, bf16 hi/lo, fragment-order + swizzle
            #pragma unroll
            for (int i = 0; i < 2; ++i) {
                int id = i * 512 + t;
                int u = id & 3, code = id >> 2;        // code 0..255
                const float* src = cb + (size_t)(kc * 256 + code) * D_DIM + d0 + u * 8;
                u32x4 hv, lv;
                split8(src, hv, lv);
                int off = code * 64 + SWZ(code, u * 16);
                *(u32x4*)(sm + OFF_HEB + off) = hv;
                *(u32x4*)(sm + OFF_LEB + off) = lv;
            }
            // stage A: 64 m x 32 d from zfp
            {
                int m = (t >> 2) & 63, u = t & 3, arr = t >> 8;
                const float* zr = zfp + m * ZFP_ROW + d0 + u * 8;
                u32x4 hv, lv;
                split8(zr, hv, lv);
                int off = m * 64 + SWZ(m, u * 16);
                *(u32x4*)(sm + (arr ? OFF_LZA : OFF_HZA) + off) = arr ? lv : hv;
            }
            __syncthreads();

            // compute: wave tile 16 m x 128 codes, 8 subtiles of 16x16
            int arow = wm * 16 + l15;
            int aoff = arow * 64 + SWZ(arow, (l >> 4) * 16);
            short8 hzF = *(const short8*)(sm + OFF_HZA + aoff);
            short8 lzF = *(const short8*)(sm + OFF_LZA + aoff);
            #pragma unroll
            for (int c4 = 0; c4 < 2; ++c4) {
                short8 he[4], le[4];
                #pragma unroll
                for (int j = 0; j < 4; ++j) {
                    int codeL = wc * 128 + (c4 * 4 + j) * 16 + l15;
                    int boff = codeL * 64 + SWZ(codeL, (l >> 4) * 16);
                    he[j] = *(const short8*)(sm + OFF_HEB + boff);
                    le[j] = *(const short8*)(sm + OFF_LEB + boff);
                }
                #pragma unroll
                for (int j = 0; j < 4; ++j)
                    acc[c4*4+j] = __builtin_amdgcn_mfma_f32_16x16x32_bf16(hzF, he[j], acc[c4*4+j], 0, 0, 0);
                #pragma unroll
                for (int j = 0; j < 4; ++j)
                    acc[c4*4+j] = __builtin_amdgcn_mfma_f32_16x16x32_bf16(hzF, le[j], acc[c4*4+j], 0, 0, 0);
                #pragma unroll
                for (int j = 0; j < 4; ++j)
                    acc[c4*4+j] = __builtin_amdgcn_mfma_f32_16x16x32_bf16(lzF, he[j], acc[c4*4+j], 0, 0, 0);
            }
        }

        // ---- filter: per-row approx min (C/D: col=l&15, row=(l>>4)*4+reg) ----
        float bn[8];
        #pragma unroll
        for (int sc = 0; sc < 8; ++sc)
            bn[sc] = enorm[kc * 256 + wc * 128 + sc * 16 + l15];

        #pragma unroll
        for (int reg = 0; reg < 4; ++reg) {
            int row = wm * 16 + (l >> 4) * 4 + reg;
            float zn = znS[row];
            float vmin = 3.4e38f;
            #pragma unroll
            for (int sc = 0; sc < 8; ++sc) {
                float val = (zn + bn[sc]) - 2.0f * acc[sc][reg];
                vmin = fminf(vmin, val);
            }
            #pragma unroll
            for (int off = 8; off; off >>= 1) vmin = fminf(vmin, __shfl_xor(vmin, off));
            if (l15 == 0) atomicMin(&rminU[row], __float_as_uint(vmin));
        }
        __syncthreads();

        // ---- scan: append candidates (m,k) within Delta of row min ----
        #pragma unroll
        for (int reg = 0; reg < 4; ++reg) {
            int row = wm * 16 + (l >> 4) * 4 + reg;
            float thr = __uint_as_float(rminU[row]) + dltS[row];
            float zn = znS[row];
            #pragma unroll
            for (int sc = 0; sc < 8; ++sc) {
                float val = (zn + bn[sc]) - 2.0f * acc[sc][reg];
                if (val <= thr) {
                    int slot = atomicAdd(cntP, 1);
                    int kg = kc * 256 + wc * 128 + sc * 16 + l15;
                    if (slot < LIST_CAP) listU[slot] = ((unsigned)row << 16) | (unsigned)kg;
                    else *ovfP = 1;
                }
            }
        }
        __syncthreads();   // scan complete before next kc resets rmin / restages
    }

    // ---- 4) exact rescore + merge (two-stage: val bits, then lowest k) ----
    const int n = min(*cntP, LIST_CAP);
    const int isovf = *ovfP;
    if (!isovf) {
        for (int i = t; i < n; i += THREADS) {
            unsigned e = listU[i];
            float val = exact_val(sm, cb, enorm, (int)(e >> 16), (int)(e & 0xFFFFu));
            atomicMin(&rbv[e >> 16], __float_as_uint(val));
        }
        __syncthreads();
        for (int i = t; i < n; i += THREADS) {
            unsigned e = listU[i];
            int m = (int)(e >> 16), k = (int)(e & 0xFFFFu);
            float val = exact_val(sm, cb, enorm, m, k);
            if (__float_as_uint(val) == rbv[m]) atomicMin(&rbk[m], (unsigned)k);
        }
    } else {
        // statistical freak: brute-force exact argmin (still fully correct)
        for (int id = t; id < MT * 1024; id += THREADS) {
            float val = exact_val(sm, cb, enorm, id >> 10, id & 1023);
            atomicMin(&rbv[id >> 10], __float_as_uint(val));
        }
        __syncthreads();
        for (int id = t; id < MT * 1024; id += THREADS) {
            int m = id >> 10, k = id & 1023;
            float val = exact_val(sm, cb, enorm, m, k);
            if (__float_as_uint(val) == rbv[m]) atomicMin(&rbk[m], (unsigned)k);
        }
    }
    __syncthreads();

    if (t < 64) {
        int k = (int)rbk[t];
        bestm[t] = k;
        out[IDX_OFF + (size_t)blk * MT + t] = (float)k;
    }
    __syncthreads();

    // ---- 5) epilogue: gather codebook rows (L2), z from LDS, loss ----
    float lsum = 0.f;
    const size_t zq_base = (size_t)b * D_DIM * HW + p0;
    for (int i2 = t; i2 < D_DIM * MT / 4; i2 += THREADS) {
        int p = i2 & (MT - 1), d4 = i2 >> 6;
        int idx = bestm[p];
        f32x4 cv = *(const f32x4*)(cb + (size_t)idx * D_DIM + d4 * 4);
        const float* zr = zfp + p * ZFP_ROW + d4 * 4;
        float z0 = zr[0], z1 = zr[1], z2 = zr[2], z3 = zr[3];
        float e0 = cv.x - z0, e1 = cv.y - z1, e2 = cv.z - z2, e3 = cv.w - z3;
        lsum = fmaf(e0, e0, lsum); lsum = fmaf(e1, e1, lsum);
        lsum = fmaf(e2, e2, lsum); lsum = fmaf(e3, e3, lsum);
        out[zq_base + (size_t)(d4 * 4 + 0) * HW + p] = cv.x;
        out[zq_base + (size_t)(d4 * 4 + 1) * HW + p] = cv.y;
        out[zq_base + (size_t)(d4 * 4 + 2) * HW + p] = cv.z;
        out[zq_base + (size_t)(d4 * 4 + 3) * HW + p] = cv.w;
    }
    #pragma unroll
    for (int off = 32; off; off >>= 1) lsum += __shfl_xor(lsum, off);
    __syncthreads();
    float* lscr = (float*)(sm + OFF_LIST);   // list no longer needed
    if ((t & 63) == 0) lscr[t >> 6] = lsum;
    __syncthreads();
    if (t == 0) {
        float s = 0.f;
        #pragma unroll
        for (int w = 0; w < 8; ++w) s += lscr[w];
        atomicAdd(out + LOSS_OFF, s * (1.25f / 8388608.f));
    }
}

extern "C" void kernel_launch(void* const* d_in, const int* in_sizes, int n_in,
                              void* d_out, int out_size, void* d_ws, size_t ws_size,
                              hipStream_t stream) {
    const float* z  = (const float*)d_in[0];
    const float* cb = (const float*)d_in[1];
    float* out = (float*)d_out;
    float* enorm = (float*)d_ws;

    hipMemsetAsync(out + LOSS_OFF, 0, sizeof(float), stream);

    enorm_kernel<<<256, 256, 0, stream>>>(cb, enorm);

    hipFuncSetAttribute((const void*)vq_kernel,
                        hipFuncAttributeMaxDynamicSharedMemorySize, SMEM_BYTES);
    vq_kernel<<<512, THREADS, SMEM_BYTES, stream>>>(z, cb, enorm, out);
}

// Round 14
// 252.921 us; speedup vs baseline: 1.3021x; 1.0812x over previous
//
#include <hip/hip_runtime.h>
#include <stdint.h>

// VQ-VAE codebook quantization, MI355X (gfx950) — MFMA filter + exact rescore.
// z: [32, 256, 32, 32] fp32 ; codebook: [1024, 256] fp32
// outputs (concat fp32): z_q [32,256,32,32] (8388608) | idx [32768] | loss [1]
//
// R14 = R13 made workspace-safe. R13's bench died at infra level
// ("container failed twice"); R13 was also the first round writing ~1MB to
// d_ws without checking ws_size — possible OOB scribble. Now kernel_launch
// branches on ws_size: pre-split codebook path if it fits, else a
// template fallback that splits B during staging (R12-proven) while keeping
// every other R13 improvement (A-frags in registers, no zfp tile, 42.5KB
// LDS -> 2 blocks/CU, conflict-free swizzle).
//
// Design (verified R12): 3-pass MFMA bf16 hi/lo dot, bound
// |err| <= 3*2^-14*||z||*||e|| + 1e-6; Delta = 1.15e-5*sqrt(zn)+9.5e-5;
// exact fp32 rescore + two-stage u32 atomicMin merge = numpy tie semantics;
// list overflow -> brute-force exact fallback.

#define D_DIM   256
#define HW      1024
#define MT      64       // m rows per block
#define THREADS 512
#define LIST_CAP 2048

#define ZQ_OFF   0
#define IDX_OFF  8388608
#define LOSS_OFF 8421376

typedef __attribute__((ext_vector_type(8))) short  short8;
typedef __attribute__((ext_vector_type(4))) float  f32x4;
typedef __attribute__((ext_vector_type(4))) unsigned int u32x4;

// ---- LDS layout (bytes) ----
#define OFF_HEB   0                      // 256 codes * 64 B = 16384 (swizzled bf16 hi)
#define OFF_LEB   16384                  // 16384 (lo)
#define OFF_LIST  32768                  // 2048 * 4 = 8192
#define OFF_ZN    40960                  // 64 f32
#define OFF_DLT   41216                  // 64 f32
#define OFF_RMIN  41472                  // 64 u32
#define OFF_RBV   41728                  // 64 u32
#define OFF_RBK   41984                  // 64 u32
#define OFF_BESTM 42240                  // 64 i32
#define OFF_CNT   42496                  // i32
#define OFF_OVF   42500                  // i32
#define SMEM_BYTES 42512

// in-row XOR swizzle: slot(u) ^= (row>>1)&3  (bits 4-5 only, bijective in 64B)
#define SWZ(rowi, u16) (((u16) ^ ((((rowi) >> 1) & 3) << 4)))

#define WS_B_OFF   4096        // split-B region starts after enorm
#define WS_B_BYTES 1048576     // 32 chunks * 32 KB
#define WS_NEEDED  (WS_B_OFF + WS_B_BYTES)

extern __shared__ char smc[];

// ws[0..4K): enorm[k] = fp32 sum of cb[k][d]^2
__global__ void enorm_kernel(const float* __restrict__ cb, float* __restrict__ enorm) {
    int gt = blockIdx.x * blockDim.x + threadIdx.x;
    int k = gt >> 6;
    int lane = gt & 63;
    const float4* row = (const float4*)(cb + (size_t)k * D_DIM);
    float4 v = row[lane];
    float s = fmaf(v.x, v.x, fmaf(v.y, v.y, fmaf(v.z, v.z, v.w * v.w)));
    #pragma unroll
    for (int off = 32; off; off >>= 1) s += __shfl_xor(s, off);
    if (lane == 0) enorm[k] = s;
}

__device__ __forceinline__ void split2(float a, float b, unsigned &hi, unsigned &lo) {
    unsigned ba = __float_as_uint(a), bb = __float_as_uint(b);
    unsigned ha = ba & 0xFFFF0000u, hb = bb & 0xFFFF0000u;
    float ra = a - __uint_as_float(ha);     // exact (same-exponent split)
    float rb = b - __uint_as_float(hb);
    hi = (ha >> 16) | hb;                   // bf16 pair: low half = first elem
    lo = (__float_as_uint(ra) >> 16) | (__float_as_uint(rb) & 0xFFFF0000u);
}

// pack 8 consecutive floats into bf16-hi/lo u32x4 fragments
__device__ __forceinline__ void split8(const float* src, u32x4 &hv, u32x4 &lv) {
    f32x4 A0 = *(const f32x4*)(src);
    f32x4 A1 = *(const f32x4*)(src + 4);
    unsigned h0, l0, h1, l1, h2, l2, h3, l3;
    split2(A0.x, A0.y, h0, l0);
    split2(A0.z, A0.w, h1, l1);
    split2(A1.x, A1.y, h2, l2);
    split2(A1.z, A1.w, h3, l3);
    hv.x = h0; hv.y = h1; hv.z = h2; hv.w = h3;
    lv.x = l0; lv.y = l1; lv.z = l2; lv.w = l3;
}

// ws[4K..4K+1M): codebook split to bf16 hi/lo, fragment-ordered, pre-swizzled.
// chunk g = kc*8+s (32 KB each): [0,16K) hi frags, [16K,32K) lo frags;
// u32x4 index within = code*4 + slot, holding frag(code, u = slot^key(code)).
__global__ void split_kernel(const float* __restrict__ cb, char* __restrict__ wsB) {
    int id = blockIdx.x * blockDim.x + threadIdx.x;   // 32768 tasks
    int g = id >> 10, rem = id & 1023, code = rem >> 2, slot = rem & 3;
    int kc = g >> 3, s = g & 7;
    int u = slot ^ ((code >> 1) & 3);
    const float* src = cb + (size_t)(kc * 256 + code) * D_DIM + s * 32 + u * 8;
    u32x4 hv, lv;
    split8(src, hv, lv);
    char* dst = wsB + (size_t)g * 32768 + (size_t)(code * 4 + slot) * 16;
    *(u32x4*)dst = hv;
    *(u32x4*)(dst + 16384) = lv;
}

// exact np-style distance from GLOBAL z (L2-hot tile); __noinline__ so both
// rescore passes produce BIT-IDENTICAL values (equality-gated k-merge).
__device__ __noinline__ float exact_val(const float* zcol, const float* cb,
                                        const float* enorm, const float* znArr,
                                        int m, int k) {
    const float* cr = cb + (size_t)k * D_DIM;
    float dot = 0.f;
    #pragma unroll 8
    for (int d = 0; d < D_DIM; ++d) dot = fmaf(zcol[(size_t)d * HW + m], cr[d], dot);
    return (znArr[m] + enorm[k]) - 2.0f * dot;
}

template <int PRESPLIT>
__global__ __launch_bounds__(THREADS, 2)
void vq_kernel(const float* __restrict__ z, const float* __restrict__ cb,
               const float* __restrict__ enorm, const char* __restrict__ wsB,
               float* __restrict__ out)
{
    char* sm = smc;
    float*    znS   = (float*)(sm + OFF_ZN);
    float*    dltS  = (float*)(sm + OFF_DLT);
    unsigned* rminU = (unsigned*)(sm + OFF_RMIN);
    unsigned* rbv   = (unsigned*)(sm + OFF_RBV);
    unsigned* rbk   = (unsigned*)(sm + OFF_RBK);
    int*      bestm = (int*)(sm + OFF_BESTM);
    unsigned* listU = (unsigned*)(sm + OFF_LIST);
    int*      cntP  = (int*)(sm + OFF_CNT);
    int*      ovfP  = (int*)(sm + OFF_OVF);

    const int t   = threadIdx.x;
    const int blk = blockIdx.x;              // 512 blocks = 2/CU
    const int b   = blk >> 4;
    const int p0  = (blk & 15) * MT;
    const float* zb   = z + (size_t)b * D_DIM * HW;
    const float* zcol = zb + p0;             // z[d][p0+m] = zcol[d*HW + m]

    // ---- 1) znorm[m] from global (coalesced); fp64 partials in HEB scratch ----
    {
        int m = t & 63, q = t >> 6;
        const float* col = zcol + m;
        double zp = 0.0;
        #pragma unroll 8
        for (int d = q * 32; d < q * 32 + 32; ++d) {
            double v = (double)col[(size_t)d * HW];
            zp += v * v;
        }
        double* zscr = (double*)(sm + OFF_HEB);        // 4 KB scratch in HEB
        zscr[q * 64 + m] = zp;
    }
    __syncthreads();
    if (t < 64) {
        double* zscr = (double*)(sm + OFF_HEB);
        double s = 0.0;
        #pragma unroll
        for (int q = 0; q < 8; ++q) s += zscr[q * 64 + t];
        float zn = (float)s;
        znS[t]  = zn;
        dltS[t] = 1.15e-5f * sqrtf(zn) + 9.5e-5f;      // rigorous capture window
        rbv[t]  = 0x7f800000u;                         // +inf bits
        rbk[t]  = 0xFFFFFFFFu;
    }
    if (t == 0) { *cntP = 0; *ovfP = 0; }

    // ---- 2) A-fragments in REGISTERS: wave's 16 rows, all 256 d, hi+lo ----
    const int l   = t & 63;
    const int wid = t >> 6;
    const int wm  = wid & 3;      // 4 m-subtiles of 16 (wc pairs duplicate A)
    const int wc  = wid >> 2;     // 2 code-halves of 128
    const int l15 = l & 15;
    const int hi4 = l >> 4;       // k-slot group within fragment

    short8 AH[8], AL[8];
    {
        const float* zA = zcol + wm * 16 + l15;   // this lane's A row
        #pragma unroll
        for (int s = 0; s < 8; ++s) {
            const float* ap = zA + (size_t)(s * 32 + hi4 * 8) * HW;
            float v0 = ap[0];
            float v1 = ap[(size_t)1 * HW];
            float v2 = ap[(size_t)2 * HW];
            float v3 = ap[(size_t)3 * HW];
            float v4 = ap[(size_t)4 * HW];
            float v5 = ap[(size_t)5 * HW];
            float v6 = ap[(size_t)6 * HW];
            float v7 = ap[(size_t)7 * HW];
            unsigned h0, l0, h1, l1, h2, l2, h3, l3;
            split2(v0, v1, h0, l0);
            split2(v2, v3, h1, l1);
            split2(v4, v5, h2, l2);
            split2(v6, v7, h3, l3);
            u32x4 hv; hv.x = h0; hv.y = h1; hv.z = h2; hv.w = h3;
            u32x4 lv; lv.x = l0; lv.y = l1; lv.z = l2; lv.w = l3;
            AH[s] = __builtin_bit_cast(short8, hv);
            AL[s] = __builtin_bit_cast(short8, lv);
        }
    }
    __syncthreads();   // zscr reads done before B staging overwrites HEB

    // ---- 3) kc loop: 4 quarters of 256 codes ----
    for (int kc = 0; kc < 4; ++kc) {
        if (t < 64) rminU[t] = 0x7f800000u;

        f32x4 acc[8];
        #pragma unroll
        for (int sc = 0; sc < 8; ++sc) acc[sc] = (f32x4){0.f, 0.f, 0.f, 0.f};

        #pragma unroll
        for (int s = 0; s < 8; ++s) {
            __syncthreads();   // prev step's fragment reads done (WAR); publishes rmin reset
            if (PRESPLIT) {
                // stage B from pre-split ws: coalesced 16B loads, LINEAR ds_write_b128
                const char* src = wsB + (size_t)(kc * 8 + s) * 32768;
                #pragma unroll
                for (int i = 0; i < 2; ++i) {
                    int id = i * 512 + t;
                    u32x4 hv = *(const u32x4*)(src + (size_t)id * 16);
                    u32x4 lv = *(const u32x4*)(src + 16384 + (size_t)id * 16);
                    *(u32x4*)(sm + OFF_HEB + id * 16) = hv;
                    *(u32x4*)(sm + OFF_LEB + id * 16) = lv;
                }
            } else {
                // fallback: split fp32 cb on the fly (R12-proven staging)
                #pragma unroll
                for (int i = 0; i < 2; ++i) {
                    int id = i * 512 + t;
                    int u = id & 3, code = id >> 2;
                    const float* srcf = cb + (size_t)(kc * 256 + code) * D_DIM + s * 32 + u * 8;
                    u32x4 hv, lv;
                    split8(srcf, hv, lv);
                    int off = code * 64 + SWZ(code, u * 16);
                    *(u32x4*)(sm + OFF_HEB + off) = hv;
                    *(u32x4*)(sm + OFF_LEB + off) = lv;
                }
            }
            __syncthreads();   // tile visible

            // compute: wave tile 16 m x 128 codes, 8 subtiles of 16x16
            const short8 hzF = AH[s];
            const short8 lzF = AL[s];
            #pragma unroll
            for (int c4 = 0; c4 < 2; ++c4) {
                short8 he[4], le[4];
                #pragma unroll
                for (int j = 0; j < 4; ++j) {
                    int codeL = wc * 128 + (c4 * 4 + j) * 16 + l15;
                    int boff = codeL * 64 + SWZ(codeL, hi4 * 16);
                    he[j] = *(const short8*)(sm + OFF_HEB + boff);
                    le[j] = *(const short8*)(sm + OFF_LEB + boff);
                }
                #pragma unroll
                for (int j = 0; j < 4; ++j)
                    acc[c4*4+j] = __builtin_amdgcn_mfma_f32_16x16x32_bf16(hzF, he[j], acc[c4*4+j], 0, 0, 0);
                #pragma unroll
                for (int j = 0; j < 4; ++j)
                    acc[c4*4+j] = __builtin_amdgcn_mfma_f32_16x16x32_bf16(hzF, le[j], acc[c4*4+j], 0, 0, 0);
                #pragma unroll
                for (int j = 0; j < 4; ++j)
                    acc[c4*4+j] = __builtin_amdgcn_mfma_f32_16x16x32_bf16(lzF, he[j], acc[c4*4+j], 0, 0, 0);
            }
        }

        // ---- filter: per-row approx min (C/D: col=l&15, row=(l>>4)*4+reg) ----
        float bn[8];
        #pragma unroll
        for (int sc = 0; sc < 8; ++sc)
            bn[sc] = enorm[kc * 256 + wc * 128 + sc * 16 + l15];

        #pragma unroll
        for (int reg = 0; reg < 4; ++reg) {
            int row = wm * 16 + hi4 * 4 + reg;
            float zn = znS[row];
            float vmin = 3.4e38f;
            #pragma unroll
            for (int sc = 0; sc < 8; ++sc) {
                float val = (zn + bn[sc]) - 2.0f * acc[sc][reg];
                vmin = fminf(vmin, val);
            }
            #pragma unroll
            for (int off = 8; off; off >>= 1) vmin = fminf(vmin, __shfl_xor(vmin, off));
            if (l15 == 0) atomicMin(&rminU[row], __float_as_uint(vmin));
        }
        __syncthreads();

        // ---- scan: append candidates (m,k) within Delta of row min ----
        #pragma unroll
        for (int reg = 0; reg < 4; ++reg) {
            int row = wm * 16 + hi4 * 4 + reg;
            float thr = __uint_as_float(rminU[row]) + dltS[row];
            float zn = znS[row];
            #pragma unroll
            for (int sc = 0; sc < 8; ++sc) {
                float val = (zn + bn[sc]) - 2.0f * acc[sc][reg];
                if (val <= thr) {
                    int slot = atomicAdd(cntP, 1);
                    int kg = kc * 256 + wc * 128 + sc * 16 + l15;
                    if (slot < LIST_CAP) listU[slot] = ((unsigned)row << 16) | (unsigned)kg;
                    else *ovfP = 1;
                }
            }
        }
        __syncthreads();   // scan complete before next kc resets rmin / restages
    }

    // ---- 4) exact rescore + merge (two-stage: val bits, then lowest k) ----
    const int n = min(*cntP, LIST_CAP);
    const int isovf = *ovfP;
    if (!isovf) {
        for (int i = t; i < n; i += THREADS) {
            unsigned e = listU[i];
            float val = exact_val(zcol, cb, enorm, znS, (int)(e >> 16), (int)(e & 0xFFFFu));
            atomicMin(&rbv[e >> 16], __float_as_uint(val));
        }
        __syncthreads();
        for (int i = t; i < n; i += THREADS) {
            unsigned e = listU[i];
            int m = (int)(e >> 16), k = (int)(e & 0xFFFFu);
            float val = exact_val(zcol, cb, enorm, znS, m, k);
            if (__float_as_uint(val) == rbv[m]) atomicMin(&rbk[m], (unsigned)k);
        }
    } else {
        // statistical freak: brute-force exact argmin (still fully correct)
        for (int id = t; id < MT * 1024; id += THREADS) {
            float val = exact_val(zcol, cb, enorm, znS, id >> 10, id & 1023);
            atomicMin(&rbv[id >> 10], __float_as_uint(val));
        }
        __syncthreads();
        for (int id = t; id < MT * 1024; id += THREADS) {
            int m = id >> 10, k = id & 1023;
            float val = exact_val(zcol, cb, enorm, znS, m, k);
            if (__float_as_uint(val) == rbv[m]) atomicMin(&rbk[m], (unsigned)k);
        }
    }
    __syncthreads();

    if (t < 64) {
        int k = (int)rbk[t];
        bestm[t] = k;
        out[IDX_OFF + (size_t)blk * MT + t] = (float)k;
    }
    __syncthreads();

    // ---- 5) epilogue: gather codebook rows (L2), z from global (L2-hot),
    //      write z_q coalesced, loss ----
    float lsum = 0.f;
    const size_t zq_base = (size_t)b * D_DIM * HW + p0;
    for (int i2 = t; i2 < D_DIM * MT / 4; i2 += THREADS) {
        int p = i2 & (MT - 1), d4 = i2 >> 6;
        int idx = bestm[p];
        f32x4 cv = *(const f32x4*)(cb + (size_t)idx * D_DIM + d4 * 4);
        const float* zp = zcol + p;
        float z0 = zp[(size_t)(d4 * 4 + 0) * HW];
        float z1 = zp[(size_t)(d4 * 4 + 1) * HW];
        float z2 = zp[(size_t)(d4 * 4 + 2) * HW];
        float z3 = zp[(size_t)(d4 * 4 + 3) * HW];
        float e0 = cv.x - z0, e1 = cv.y - z1, e2 = cv.z - z2, e3 = cv.w - z3;
        lsum = fmaf(e0, e0, lsum); lsum = fmaf(e1, e1, lsum);
        lsum = fmaf(e2, e2, lsum); lsum = fmaf(e3, e3, lsum);
        out[zq_base + (size_t)(d4 * 4 + 0) * HW + p] = cv.x;
        out[zq_base + (size_t)(d4 * 4 + 1) * HW + p] = cv.y;
        out[zq_base + (size_t)(d4 * 4 + 2) * HW + p] = cv.z;
        out[zq_base + (size_t)(d4 * 4 + 3) * HW + p] = cv.w;
    }
    #pragma unroll
    for (int off = 32; off; off >>= 1) lsum += __shfl_xor(lsum, off);
    __syncthreads();
    float* lscr = (float*)(sm + OFF_LIST);   // list no longer needed
    if ((t & 63) == 0) lscr[t >> 6] = lsum;
    __syncthreads();
    if (t == 0) {
        float s = 0.f;
        #pragma unroll
        for (int w = 0; w < 8; ++w) s += lscr[w];
        atomicAdd(out + LOSS_OFF, s * (1.25f / 8388608.f));
    }
}

extern "C" void kernel_launch(void* const* d_in, const int* in_sizes, int n_in,
                              void* d_out, int out_size, void* d_ws, size_t ws_size,
                              hipStream_t stream) {
    const float* z  = (const float*)d_in[0];
    const float* cb = (const float*)d_in[1];
    float* out = (float*)d_out;
    float* enorm = (float*)d_ws;
    char*  wsB   = (char*)d_ws + WS_B_OFF;

    hipMemsetAsync(out + LOSS_OFF, 0, sizeof(float), stream);

    enorm_kernel<<<256, 256, 0, stream>>>(cb, enorm);

    if (ws_size >= (size_t)WS_NEEDED) {
        split_kernel<<<128, 256, 0, stream>>>(cb, wsB);
        hipFuncSetAttribute((const void*)vq_kernel<1>,
                            hipFuncAttributeMaxDynamicSharedMemorySize, SMEM_BYTES);
        vq_kernel<1><<<512, THREADS, SMEM_BYTES, stream>>>(z, cb, enorm, wsB, out);
    } else {
        hipFuncSetAttribute((const void*)vq_kernel<0>,
                            hipFuncAttributeMaxDynamicSharedMemorySize, SMEM_BYTES);
        vq_kernel<0><<<512, THREADS, SMEM_BYTES, stream>>>(z, cb, enorm, wsB, out);
    }
}